// Round 14
// baseline (352.444 us; speedup 1.0000x reference)
//
#include <hip/hip_runtime.h>

typedef unsigned short u16;
typedef __attribute__((ext_vector_type(8))) short bf16x8;
typedef __attribute__((ext_vector_type(4))) float f32x4;
typedef __attribute__((ext_vector_type(2))) float f32x2;

__device__ __forceinline__ float bf2f(u16 u) { return __uint_as_float(((unsigned)u) << 16); }
__device__ __forceinline__ u16 f2bf(float f) {
  unsigned u = __float_as_uint(f);
  u += 0x7fffu + ((u >> 16) & 1u);   // RNE
  return (u16)(u >> 16);
}
__device__ __forceinline__ f32x2 bf2v(unsigned w) {
  f32x2 r;
  r.x = __uint_as_float(w << 16);
  r.y = __uint_as_float(w & 0xffff0000u);
  return r;
}

// ---------------------------------------------------------------------------
// prep: [0,nx) x->XH (hi bf16); then BC1(1024)=[bl1|br1], BC2(512)=[bl2|br2].
// ---------------------------------------------------------------------------
__global__ __launch_bounds__(256) void prep_kernel(
    const float* __restrict__ x,
    const float* __restrict__ bl1, const float* __restrict__ br1,
    const float* __restrict__ bl2, const float* __restrict__ br2,
    u16* __restrict__ XH, float* __restrict__ BC1, float* __restrict__ BC2,
    int nx, int total)
{
  int i = blockIdx.x * 256 + threadIdx.x;
  if (i >= total) return;
  if (i < nx) { XH[i] = f2bf(x[i]); return; }
  int j = i - nx;
  if (j < 1024) { BC1[j] = (j < 512) ? bl1[j] : br1[j - 512]; return; }
  int t = j - 1024;
  BC2[t] = (t < 256) ? bl2[t] : br2[t - 256];
}

// ---------------------------------------------------------------------------
// Weight transpose + split + PACK into MFMA-fragment chunk order (r13 layout).
// ---------------------------------------------------------------------------
__global__ __launch_bounds__(256) void wtrans_kernel(
    const float* __restrict__ Wl1, const float* __restrict__ Wr1,
    const float* __restrict__ Wl2, const float* __restrict__ Wr2,
    const float* __restrict__ Wjk,
    u16* __restrict__ Wp)
{
  __shared__ float T[64][65];
  int t = blockIdx.x;
  const float *Wa, *Wb; int Nhalf, lds, k0, n0, KsT, SUBS; size_t obase; bool split;
  if (t < 32) {
    int kt = t & 1, nt = t >> 1;
    k0 = kt * 64; n0 = nt * 64; obase = 0; KsT = 4; SUBS = 8; split = true;
    Wa = Wl1; Wb = Wr1; Nhalf = 512; lds = 512;
  } else if (t < 96) {
    int tt = t - 32; int kt = tt & 7, nt = tt >> 3;
    k0 = kt * 64; n0 = nt * 64; obase = 262144; KsT = 16; SUBS = 8; split = true;
    Wa = Wl2; Wb = Wr2; Nhalf = 256; lds = 256;
  } else {
    int tt = t - 96; int kt = tt % 14, nt = tt / 14;
    k0 = kt * 64; n0 = nt * 64; obase = 786432; KsT = 28; SUBS = 4; split = false;
    Wa = Wjk; Wb = nullptr; Nhalf = 128; lds = 128;
  }
  const int tid = threadIdx.x;
  const int lane = tid & 63, unit = tid >> 6;
  {
    int n = n0 + lane;
    const float* S = (n < Nhalf) ? Wa : Wb;
    int nn = (n < Nhalf) ? n : n - Nhalf;
#pragma unroll
    for (int r = 0; r < 16; ++r) {
      int kl = unit + 4 * r;
      T[kl][lane] = S[(size_t)(k0 + kl) * lds + nn];
    }
  }
  __syncthreads();
  const int tn = n0 >> 6;
#pragma unroll
  for (int u = 0; u < 2; ++u) {
    int c = unit * 2 + u;
    int ks_l = c >> 2, nc = c & 3;
    int ksg = (k0 >> 5) + ks_l;
    size_t ob = obase + ((size_t)(tn * KsT + ksg) * SUBS + nc) * 512 + lane * 8;
#pragma unroll
    for (int j = 0; j < 8; ++j) {
      float v = T[ks_l * 32 + (lane >> 4) * 8 + j][nc * 16 + (lane & 15)];
      u16 h = f2bf(v);
      Wp[ob + j] = h;
      if (split) Wp[ob + 2048 + j] = f2bf(v - bf2f(h));
    }
  }
}

// ---------------------------------------------------------------------------
// CSR build: histogram -> exclusive scan (shuffle) -> scatter srcs by dst
// ---------------------------------------------------------------------------
__global__ __launch_bounds__(256) void hist_kernel(
    const int* __restrict__ ei, int E, int ET, int* __restrict__ cnt)
{
  int e = blockIdx.x * 256 + threadIdx.x;
  if (e >= ET) return;
  int d = (e < E) ? ei[E + e] : (e - E);
  atomicAdd(&cnt[d], 1);
}

__global__ __launch_bounds__(1024) void scan_kernel(
    const int* __restrict__ cnt, int* __restrict__ rowptr, int n)
{
  __shared__ int wsum[16];
  __shared__ int carry;
  const int tid = threadIdx.x, lane = tid & 63, wv = tid >> 6;
  if (tid == 0) carry = 0;
  __syncthreads();
  for (int base = 0; base < n; base += 1024) {
    int i = base + tid;
    int v = (i < n) ? cnt[i] : 0;
    int s = v;
#pragma unroll
    for (int ofs = 1; ofs < 64; ofs <<= 1) {
      int t = __shfl_up(s, ofs);
      if (lane >= ofs) s += t;
    }
    if (lane == 63) wsum[wv] = s;
    __syncthreads();
    if (wv == 0 && lane < 16) {
      int t = wsum[lane];
#pragma unroll
      for (int ofs = 1; ofs < 16; ofs <<= 1) {
        int u = __shfl_up(t, ofs);
        if (lane >= ofs) t += u;
      }
      wsum[lane] = t;
    }
    __syncthreads();
    int waveoff = (wv == 0) ? 0 : wsum[wv - 1];
    if (i < n) rowptr[i] = carry + waveoff + s - v;
    int tot = wsum[15];
    __syncthreads();
    if (tid == 0) carry += tot;
    __syncthreads();
  }
  if (threadIdx.x == 0) rowptr[n] = carry;
}

__global__ __launch_bounds__(256) void scatter_kernel(
    const int* __restrict__ ei, int E, int ET,
    const int* __restrict__ rowptr, int* __restrict__ cur, int* __restrict__ srcs)
{
  int e = blockIdx.x * 256 + threadIdx.x;
  if (e >= ET) return;
  int s, d;
  if (e < E) { s = ei[e]; d = ei[E + e]; } else { s = e - E; d = s; }
  int pos = rowptr[d] + atomicAdd(&cur[d], 1);
  srcs[pos] = s;
}

// ---------------------------------------------------------------------------
// Edge-balanced wave partition: wave w starts at the node where cumulative
// edge count reaches w*ET/nw (binary search on rowptr).
// ---------------------------------------------------------------------------
__global__ __launch_bounds__(256) void partition_kernel(
    const int* __restrict__ rowptr, int Nn, int ET, int nw, int* __restrict__ wbeg)
{
  int w = blockIdx.x * 256 + threadIdx.x;
  if (w > nw) return;
  long long target = (long long)ET * w / nw;
  int lo = 0, hi = Nn;
  while (lo < hi) {
    int mid = (lo + hi + 1) >> 1;
    if ((long long)rowptr[mid] <= target) lo = mid; else hi = mid - 1;
  }
  wbeg[w] = lo;
}

// ---------------------------------------------------------------------------
// GEMM v10 "gemmct" (operand-swap, packed weights) — unchanged from r13.
// ---------------------------------------------------------------------------
template<int MROWS, int NW, int WPE, bool SPLIT, bool BF16OUT, int LDSU16>
__global__ __launch_bounds__(NW * 64, WPE) void gemmct_kernel(
    const u16* __restrict__ A0, int lda0, int K0,
    const u16* __restrict__ A1, int lda1, int K1,
    const u16* __restrict__ A2, int lda2, int K2,
    const u16* __restrict__ Wp, int KsT,
    int kof0, int kof1, int kof2,
    const float* __restrict__ bias,
    void* __restrict__ Cv, int ldc, int M, int N)
{
  constexpr int SUBS = SPLIT ? 8 : 4;
  __shared__ u16 ldsA[LDSU16];
  const int tid  = threadIdx.x;
  const int lane = tid & 63;
  const int wv   = tid >> 6;
  const int quad = lane >> 4;
  const int r16  = lane & 15;
  const int m0   = blockIdx.x * MROWS;

  const u16* As[3]   = {A0, A1, A2};
  const int  Ks[3]   = {K0, K1, K2};
  const int  ldas[3] = {lda0, lda1, lda2};
  const int  kofs[3] = {kof0, kof1, kof2};

  int soff[3];
  int so = 0;
#pragma unroll
  for (int s = 0; s < 3; ++s) {
    const int K = Ks[s];
    soff[s] = so;
    if (K == 0) continue;
    const int stride = K + 8;
    const int cpr = K >> 3;
    const int sh  = 32 - __clz(cpr - 1);
    const int tot = MROWS << sh;
    for (int c = tid; c < tot; c += NW * 64) {
      int row = c >> sh, kc = c & ((1 << sh) - 1);
      if (kc < cpr) {
        int sr = m0 + row; if (sr >= M) sr = M - 1;
        uint4 v = *reinterpret_cast<const uint4*>(As[s] + (size_t)sr * ldas[s] + kc * 8);
        *reinterpret_cast<uint4*>(&ldsA[so + row * stride + kc * 8]) = v;
      }
    }
    so += MROWS * stride;
  }
  __syncthreads();

  constexpr int MM = MROWS / 16;
  for (int n0w = wv * 64; n0w < N; n0w += NW * 64) {
    const int t = n0w >> 6;
    f32x4 acc[MM][4];
#pragma unroll
    for (int mm = 0; mm < MM; ++mm)
#pragma unroll
      for (int nc = 0; nc < 4; ++nc) acc[mm][nc] = (f32x4){0.f, 0.f, 0.f, 0.f};

#pragma unroll
    for (int s = 0; s < 3; ++s) {
      const int K = Ks[s];
      if (K == 0) continue;
      const int stride = K + 8;
      const int ksb = kofs[s] >> 5;
      const u16* lbase = &ldsA[soff[s] + r16 * stride + quad * 8];

#pragma unroll 2
      for (int k0 = 0; k0 < K; k0 += 32) {
        const int ks = ksb + (k0 >> 5);
        const u16* ch = Wp + (((size_t)(t * KsT + ks) * SUBS) << 9) + lane * 8;
        bf16x8 af[MM];
#pragma unroll
        for (int mm = 0; mm < MM; ++mm)
          af[mm] = *reinterpret_cast<const bf16x8*>(lbase + mm * 16 * stride + k0);
        bf16x8 whf[4], wlf[4];
#pragma unroll
        for (int nc = 0; nc < 4; ++nc) {
          whf[nc] = *reinterpret_cast<const bf16x8*>(ch + (nc << 9));
          if (SPLIT) wlf[nc] = *reinterpret_cast<const bf16x8*>(ch + ((4 + nc) << 9));
        }
#pragma unroll
        for (int mm = 0; mm < MM; ++mm)
#pragma unroll
          for (int nc = 0; nc < 4; ++nc) {
            acc[mm][nc] = __builtin_amdgcn_mfma_f32_16x16x32_bf16(whf[nc], af[mm], acc[mm][nc], 0, 0, 0);
            if (SPLIT)
              acc[mm][nc] = __builtin_amdgcn_mfma_f32_16x16x32_bf16(wlf[nc], af[mm], acc[mm][nc], 0, 0, 0);
          }
      }
    }

#pragma unroll
    for (int mm = 0; mm < MM; ++mm) {
      const int m = m0 + mm * 16 + r16;
      if (m >= M) continue;
#pragma unroll
      for (int nc = 0; nc < 4; ++nc) {
        const int n = n0w + nc * 16 + quad * 4;
        float b0 = 0.f, b1 = 0.f, b2 = 0.f, b3 = 0.f;
        if (bias) {
          float4 bv = *reinterpret_cast<const float4*>(bias + n);
          b0 = bv.x; b1 = bv.y; b2 = bv.z; b3 = bv.w;
        }
        float v0 = acc[mm][nc][0] + b0;
        float v1 = acc[mm][nc][1] + b1;
        float v2 = acc[mm][nc][2] + b2;
        float v3 = acc[mm][nc][3] + b3;
        if (BF16OUT) {
          ushort4 o = { f2bf(v0), f2bf(v1), f2bf(v2), f2bf(v3) };
          *reinterpret_cast<ushort4*>((u16*)Cv + (size_t)m * ldc + n) = o;
        } else {
          float4 o = { v0, v1, v2, v3 };
          *reinterpret_cast<float4*>((float*)Cv + (size_t)m * ldc + n) = o;
        }
      }
    }
  }
}

// ---------------------------------------------------------------------------
// Fused GATv2 aggregation, packed-f32 (v_pk_*) edge math, edge-balanced
// per-wave node ranges (wbeg from partition_kernel). Softmax referenced to
// first edge's logit; lrelu(v) = max(v, 0.2v).
// XLR row (u16): [xl(0..D-1) | xr(D..2D-1)].
// ---------------------------------------------------------------------------
template<int NV2>   // f32x2 words per lane: 4 (C=64) or 2 (C=32)
__device__ __forceinline__ void load_row2(const u16* p, f32x2* dst) {
  if constexpr (NV2 == 4) {
    uint4 t = *reinterpret_cast<const uint4*>(p);
    dst[0] = bf2v(t.x); dst[1] = bf2v(t.y); dst[2] = bf2v(t.z); dst[3] = bf2v(t.w);
  } else {
    uint2 t = *reinterpret_cast<const uint2*>(p);
    dst[0] = bf2v(t.x); dst[1] = bf2v(t.y);
  }
}

template<int C>
__global__ __launch_bounds__(256) void gat_node_kernel(
    const u16* __restrict__ XLR,
    const int* __restrict__ rowptr, const int* __restrict__ srcs,
    const float* __restrict__ att, const float* __restrict__ bias,
    u16* __restrict__ Hh, const int* __restrict__ wbeg, int nwaves)
{
  constexpr int D = C * 8;
  constexpr int VPL = D / 64;
  constexpr int NV2 = VPL / 2;
  const int lane = threadIdx.x & 63;
  const int wv  = (blockIdx.x * 256 + threadIdx.x) >> 6;
  if (wv >= nwaves) return;

  f32x2 attR[NV2], biasR[NV2];
#pragma unroll
  for (int w = 0; w < NV2; ++w) {
    attR[w].x  = att[lane * VPL + 2 * w];
    attR[w].y  = att[lane * VPL + 2 * w + 1];
    biasR[w].x = bias[lane * VPL + 2 * w];
    biasR[w].y = bias[lane * VPL + 2 * w + 1];
  }

  const int dbeg = wbeg[wv], dend = wbeg[wv + 1];
  for (int d = dbeg; d < dend; ++d) {
    f32x2 xr[NV2];
    load_row2<NV2>(XLR + (size_t)d * (2 * D) + D + lane * VPL, xr);

    const int jb = rowptr[d], je = rowptr[d + 1];

    // first edge = softmax reference (acc initialized to its xl row)
    f32x2 acc[NV2];
    load_row2<NV2>(XLR + (size_t)srcs[jb] * (2 * D) + lane * VPL, acc);
    f32x2 p02 = {0.f, 0.f};
#pragma unroll
    for (int w = 0; w < NV2; ++w) {
      f32x2 va = acc[w] + xr[w];
      f32x2 vm = __builtin_elementwise_max(va, 0.2f * va);
      p02 += attR[w] * vm;
    }
    float p0 = p02.x + p02.y;
    p0 += __shfl_xor(p0, 1);
    p0 += __shfl_xor(p0, 2);
    p0 += __shfl_xor(p0, 4);
    float den = 1.f;

    int j = jb + 1;
    for (; j + 1 < je; j += 2) {
      f32x2 xa[NV2], xb[NV2];
      load_row2<NV2>(XLR + (size_t)srcs[j]     * (2 * D) + lane * VPL, xa);
      load_row2<NV2>(XLR + (size_t)srcs[j + 1] * (2 * D) + lane * VPL, xb);
      f32x2 pa2 = {0.f, 0.f}, pb2 = {0.f, 0.f};
#pragma unroll
      for (int w = 0; w < NV2; ++w) {
        f32x2 va = xa[w] + xr[w];
        f32x2 vb = xb[w] + xr[w];
        f32x2 vam = __builtin_elementwise_max(va, 0.2f * va);
        f32x2 vbm = __builtin_elementwise_max(vb, 0.2f * vb);
        pa2 += attR[w] * vam;
        pb2 += attR[w] * vbm;
      }
      float pa = pa2.x + pa2.y, pb = pb2.x + pb2.y;
      pa += __shfl_xor(pa, 1); pb += __shfl_xor(pb, 1);
      pa += __shfl_xor(pa, 2); pb += __shfl_xor(pb, 2);
      pa += __shfl_xor(pa, 4); pb += __shfl_xor(pb, 4);
      const float ea = __expf(pa - p0);
      const float eb = __expf(pb - p0);
      den += ea + eb;
      const f32x2 ea2 = {ea, ea}, eb2 = {eb, eb};
#pragma unroll
      for (int w = 0; w < NV2; ++w)
        acc[w] += ea2 * xa[w] + eb2 * xb[w];
    }
    if (j < je) {
      f32x2 xa[NV2];
      load_row2<NV2>(XLR + (size_t)srcs[j] * (2 * D) + lane * VPL, xa);
      f32x2 pa2 = {0.f, 0.f};
#pragma unroll
      for (int w = 0; w < NV2; ++w) {
        f32x2 va = xa[w] + xr[w];
        f32x2 vam = __builtin_elementwise_max(va, 0.2f * va);
        pa2 += attR[w] * vam;
      }
      float pa = pa2.x + pa2.y;
      pa += __shfl_xor(pa, 1);
      pa += __shfl_xor(pa, 2);
      pa += __shfl_xor(pa, 4);
      const float ea = __expf(pa - p0);
      den += ea;
      const f32x2 ea2 = {ea, ea};
#pragma unroll
      for (int w = 0; w < NV2; ++w) acc[w] += ea2 * xa[w];
    }

    const float inv = 1.f / den;
    const f32x2 inv2 = {inv, inv};
    u16* hh = Hh + (size_t)d * D + lane * VPL;
#pragma unroll
    for (int w = 0; w < NV2; ++w) {
      f32x2 v = acc[w] * inv2 + biasR[w];
      float v0 = v.x > 0.f ? v.x : (__expf(v.x) - 1.f);
      float v1 = v.y > 0.f ? v.y : (__expf(v.y) - 1.f);
      hh[2 * w]     = f2bf(v0);
      hh[2 * w + 1] = f2bf(v1);
    }
  }
}

// ---------------------------------------------------------------------------

extern "C" void kernel_launch(void* const* d_in, const int* in_sizes, int n_in,
                              void* d_out, int out_size, void* d_ws, size_t ws_size,
                              hipStream_t stream) {
  const float* x     = (const float*)d_in[0];
  const int*   ei    = (const int*)d_in[1];
  const float* Wl1   = (const float*)d_in[2];
  const float* bl1   = (const float*)d_in[3];
  const float* Wr1   = (const float*)d_in[4];
  const float* br1   = (const float*)d_in[5];
  const float* att1  = (const float*)d_in[6];
  const float* bias1 = (const float*)d_in[7];
  const float* Wl2   = (const float*)d_in[8];
  const float* bl2   = (const float*)d_in[9];
  const float* Wr2   = (const float*)d_in[10];
  const float* br2   = (const float*)d_in[11];
  const float* att2  = (const float*)d_in[12];
  const float* bias2 = (const float*)d_in[13];
  const float* Wjk   = (const float*)d_in[14];
  const float* bjk   = (const float*)d_in[15];
  float* out = (float*)d_out;

  const int Nn = in_sizes[0] / 128;   // 20000
  const int E  = in_sizes[1] / 2;     // 320000
  const int ET = E + Nn;              // 340000

  const size_t nx = (size_t)Nn * 128;

  // packed weight region bases (u16 elements)
  const size_t oW1  = 0;
  const size_t oW2  = 262144;
  const size_t oWjk = 786432;
  const size_t npack = 901120;

  const int NWAVES = 5000;

  // workspace (~85 MB)
  char* ws = (char*)d_ws;
  size_t off = 0;
  u16* XH = (u16*)(ws + off); off += nx * 2;
  u16* Wp = (u16*)(ws + off); off += npack * 2;
  float* BC1 = (float*)(ws + off); off += 1024 * 4;
  float* BC2 = (float*)(ws + off); off += 512 * 4;
  u16* XLR1 = (u16*)(ws + off);               // [N][1024] bf16
  u16* XLR2 = XLR1;                           // [N][512]  (sequential reuse)
  off += (size_t)Nn * 1024 * 2;
  u16* H1h = (u16*)(ws + off); off += (size_t)Nn * 512 * 2;
  u16* H2h = (u16*)(ws + off); off += (size_t)Nn * 256 * 2;
  int* rowptr = (int*)(ws + off); off += (size_t)(Nn + 1) * 4;
  int* cur    = (int*)(ws + off); off += (size_t)Nn * 4;
  int* srcs   = (int*)(ws + off); off += (size_t)ET * 4;
  int* wbeg   = (int*)(ws + off); off += (size_t)(NWAVES + 1) * 4;

  const int nodeblocks = NWAVES / 4;   // 1250 blocks = 5000 waves

  // ---------------- prep + weight pack + CSR build + partition ----------------
  const int nprep = (int)(nx + 1536);
  prep_kernel<<<(nprep + 255) / 256, 256, 0, stream>>>(
      x, bl1, br1, bl2, br2, XH, BC1, BC2, (int)nx, nprep);
  wtrans_kernel<<<124, 256, 0, stream>>>(Wl1, Wr1, Wl2, Wr2, Wjk, Wp);
  hipMemsetAsync(cur, 0, (size_t)Nn * 4, stream);
  hist_kernel<<<(ET + 255) / 256, 256, 0, stream>>>(ei, E, ET, cur);
  scan_kernel<<<1, 1024, 0, stream>>>(cur, rowptr, Nn);
  partition_kernel<<<(NWAVES + 256) / 256, 256, 0, stream>>>(
      rowptr, Nn, ET, NWAVES, wbeg);
  hipMemsetAsync(cur, 0, (size_t)Nn * 4, stream);
  scatter_kernel<<<(ET + 255) / 256, 256, 0, stream>>>(ei, E, ET, rowptr, cur, srcs);

  // ---------------- Layer 1: XLR1 = XH @ [Wl1|Wr1] (2-term split) ----------
  gemmct_kernel<32, 8, 4, true, true, 32 * 136>
      <<<(Nn + 31) / 32, 512, 0, stream>>>(
      XH, 128, 128, nullptr, 0, 0, nullptr, 0, 0,
      Wp + oW1, 4, 0, 0, 0, BC1,
      XLR1, 1024, Nn, 1024);
  gat_node_kernel<64><<<nodeblocks, 256, 0, stream>>>(
      XLR1, rowptr, srcs, att1, bias1, H1h, wbeg, NWAVES);

  // ---------------- Layer 2: XLR2 = H1h @ [Wl2|Wr2] (2-term split) ---------
  gemmct_kernel<48, 8, 4, true, true, 48 * 520>
      <<<(Nn + 47) / 48, 512, 0, stream>>>(
      H1h, 512, 512, nullptr, 0, 0, nullptr, 0, 0,
      Wp + oW2, 16, 0, 0, 0, BC2,
      XLR2, 512, Nn, 512);
  gat_node_kernel<32><<<nodeblocks, 256, 0, stream>>>(
      XLR2, rowptr, srcs, att2, bias2, H2h, wbeg, NWAVES);

  // ---------------- JK: out = [x|h1|h2] @ Wjk + bjk (hi-only, f32 out) -----
  gemmct_kernel<16, 2, 1, false, false, 16 * 920>
      <<<(Nn + 15) / 16, 128, 0, stream>>>(
      XH, 128, 128, H1h, 512, 512, H2h, 256, 256,
      Wp + oWjk, 28, 0, 128, 640, bjk,
      out, 128, Nn, 128);
}

// Round 15
// 340.270 us; speedup vs baseline: 1.0358x; 1.0358x over previous
//
#include <hip/hip_runtime.h>

typedef unsigned short u16;
typedef __attribute__((ext_vector_type(8))) short bf16x8;
typedef __attribute__((ext_vector_type(4))) float f32x4;

__device__ __forceinline__ float bf2f(u16 u) { return __uint_as_float(((unsigned)u) << 16); }
__device__ __forceinline__ u16 f2bf(float f) {
  unsigned u = __float_as_uint(f);
  u += 0x7fffu + ((u >> 16) & 1u);   // RNE
  return (u16)(u >> 16);
}
__device__ __forceinline__ void bf2x2(unsigned w, float& lo, float& hi) {
  lo = __uint_as_float(w << 16);
  hi = __uint_as_float(w & 0xffff0000u);
}

// ---------------------------------------------------------------------------
// prep: [0,nx) x->XH (hi bf16); then BC1(1024)=[bl1|br1], BC2(512)=[bl2|br2].
// ---------------------------------------------------------------------------
__global__ __launch_bounds__(256) void prep_kernel(
    const float* __restrict__ x,
    const float* __restrict__ bl1, const float* __restrict__ br1,
    const float* __restrict__ bl2, const float* __restrict__ br2,
    u16* __restrict__ XH, float* __restrict__ BC1, float* __restrict__ BC2,
    int nx, int total)
{
  int i = blockIdx.x * 256 + threadIdx.x;
  if (i >= total) return;
  if (i < nx) { XH[i] = f2bf(x[i]); return; }
  int j = i - nx;
  if (j < 1024) { BC1[j] = (j < 512) ? bl1[j] : br1[j - 512]; return; }
  int t = j - 1024;
  BC2[t] = (t < 256) ? bl2[t] : br2[t - 256];
}

// ---------------------------------------------------------------------------
// Weight transpose + split + PACK into MFMA-fragment chunk order (r13 layout).
// ---------------------------------------------------------------------------
__global__ __launch_bounds__(256) void wtrans_kernel(
    const float* __restrict__ Wl1, const float* __restrict__ Wr1,
    const float* __restrict__ Wl2, const float* __restrict__ Wr2,
    const float* __restrict__ Wjk,
    u16* __restrict__ Wp)
{
  __shared__ float T[64][65];
  int t = blockIdx.x;
  const float *Wa, *Wb; int Nhalf, lds, k0, n0, KsT, SUBS; size_t obase; bool split;
  if (t < 32) {
    int kt = t & 1, nt = t >> 1;
    k0 = kt * 64; n0 = nt * 64; obase = 0; KsT = 4; SUBS = 8; split = true;
    Wa = Wl1; Wb = Wr1; Nhalf = 512; lds = 512;
  } else if (t < 96) {
    int tt = t - 32; int kt = tt & 7, nt = tt >> 3;
    k0 = kt * 64; n0 = nt * 64; obase = 262144; KsT = 16; SUBS = 8; split = true;
    Wa = Wl2; Wb = Wr2; Nhalf = 256; lds = 256;
  } else {
    int tt = t - 96; int kt = tt % 14, nt = tt / 14;
    k0 = kt * 64; n0 = nt * 64; obase = 786432; KsT = 28; SUBS = 4; split = false;
    Wa = Wjk; Wb = nullptr; Nhalf = 128; lds = 128;
  }
  const int tid = threadIdx.x;
  const int lane = tid & 63, unit = tid >> 6;
  {
    int n = n0 + lane;
    const float* S = (n < Nhalf) ? Wa : Wb;
    int nn = (n < Nhalf) ? n : n - Nhalf;
#pragma unroll
    for (int r = 0; r < 16; ++r) {
      int kl = unit + 4 * r;
      T[kl][lane] = S[(size_t)(k0 + kl) * lds + nn];
    }
  }
  __syncthreads();
  const int tn = n0 >> 6;
#pragma unroll
  for (int u = 0; u < 2; ++u) {
    int c = unit * 2 + u;
    int ks_l = c >> 2, nc = c & 3;
    int ksg = (k0 >> 5) + ks_l;
    size_t ob = obase + ((size_t)(tn * KsT + ksg) * SUBS + nc) * 512 + lane * 8;
#pragma unroll
    for (int j = 0; j < 8; ++j) {
      float v = T[ks_l * 32 + (lane >> 4) * 8 + j][nc * 16 + (lane & 15)];
      u16 h = f2bf(v);
      Wp[ob + j] = h;
      if (split) Wp[ob + 2048 + j] = f2bf(v - bf2f(h));
    }
  }
}

// ---------------------------------------------------------------------------
// CSR build: histogram -> exclusive scan (shuffle) -> scatter srcs by dst
// ---------------------------------------------------------------------------
__global__ __launch_bounds__(256) void hist_kernel(
    const int* __restrict__ ei, int E, int ET, int* __restrict__ cnt)
{
  int e = blockIdx.x * 256 + threadIdx.x;
  if (e >= ET) return;
  int d = (e < E) ? ei[E + e] : (e - E);
  atomicAdd(&cnt[d], 1);
}

__global__ __launch_bounds__(1024) void scan_kernel(
    const int* __restrict__ cnt, int* __restrict__ rowptr, int n)
{
  __shared__ int wsum[16];
  __shared__ int carry;
  const int tid = threadIdx.x, lane = tid & 63, wv = tid >> 6;
  if (tid == 0) carry = 0;
  __syncthreads();
  for (int base = 0; base < n; base += 1024) {
    int i = base + tid;
    int v = (i < n) ? cnt[i] : 0;
    int s = v;
#pragma unroll
    for (int ofs = 1; ofs < 64; ofs <<= 1) {
      int t = __shfl_up(s, ofs);
      if (lane >= ofs) s += t;
    }
    if (lane == 63) wsum[wv] = s;
    __syncthreads();
    if (wv == 0 && lane < 16) {
      int t = wsum[lane];
#pragma unroll
      for (int ofs = 1; ofs < 16; ofs <<= 1) {
        int u = __shfl_up(t, ofs);
        if (lane >= ofs) t += u;
      }
      wsum[lane] = t;
    }
    __syncthreads();
    int waveoff = (wv == 0) ? 0 : wsum[wv - 1];
    if (i < n) rowptr[i] = carry + waveoff + s - v;
    int tot = wsum[15];
    __syncthreads();
    if (tid == 0) carry += tot;
    __syncthreads();
  }
  if (threadIdx.x == 0) rowptr[n] = carry;
}

__global__ __launch_bounds__(256) void scatter_kernel(
    const int* __restrict__ ei, int E, int ET,
    const int* __restrict__ rowptr, int* __restrict__ cur, int* __restrict__ srcs)
{
  int e = blockIdx.x * 256 + threadIdx.x;
  if (e >= ET) return;
  int s, d;
  if (e < E) { s = ei[e]; d = ei[E + e]; } else { s = e - E; d = s; }
  int pos = rowptr[d] + atomicAdd(&cur[d], 1);
  srcs[pos] = s;
}

// ---------------------------------------------------------------------------
// GEMM v10 "gemmct" (operand-swap, packed weights) — unchanged from r13.
// ---------------------------------------------------------------------------
template<int MROWS, int NW, int WPE, bool SPLIT, bool BF16OUT, int LDSU16>
__global__ __launch_bounds__(NW * 64, WPE) void gemmct_kernel(
    const u16* __restrict__ A0, int lda0, int K0,
    const u16* __restrict__ A1, int lda1, int K1,
    const u16* __restrict__ A2, int lda2, int K2,
    const u16* __restrict__ Wp, int KsT,
    int kof0, int kof1, int kof2,
    const float* __restrict__ bias,
    void* __restrict__ Cv, int ldc, int M, int N)
{
  constexpr int SUBS = SPLIT ? 8 : 4;
  __shared__ u16 ldsA[LDSU16];
  const int tid  = threadIdx.x;
  const int lane = tid & 63;
  const int wv   = tid >> 6;
  const int quad = lane >> 4;
  const int r16  = lane & 15;
  const int m0   = blockIdx.x * MROWS;

  const u16* As[3]   = {A0, A1, A2};
  const int  Ks[3]   = {K0, K1, K2};
  const int  ldas[3] = {lda0, lda1, lda2};
  const int  kofs[3] = {kof0, kof1, kof2};

  int soff[3];
  int so = 0;
#pragma unroll
  for (int s = 0; s < 3; ++s) {
    const int K = Ks[s];
    soff[s] = so;
    if (K == 0) continue;
    const int stride = K + 8;
    const int cpr = K >> 3;
    const int sh  = 32 - __clz(cpr - 1);
    const int tot = MROWS << sh;
    for (int c = tid; c < tot; c += NW * 64) {
      int row = c >> sh, kc = c & ((1 << sh) - 1);
      if (kc < cpr) {
        int sr = m0 + row; if (sr >= M) sr = M - 1;
        uint4 v = *reinterpret_cast<const uint4*>(As[s] + (size_t)sr * ldas[s] + kc * 8);
        *reinterpret_cast<uint4*>(&ldsA[so + row * stride + kc * 8]) = v;
      }
    }
    so += MROWS * stride;
  }
  __syncthreads();

  constexpr int MM = MROWS / 16;
  for (int n0w = wv * 64; n0w < N; n0w += NW * 64) {
    const int t = n0w >> 6;
    f32x4 acc[MM][4];
#pragma unroll
    for (int mm = 0; mm < MM; ++mm)
#pragma unroll
      for (int nc = 0; nc < 4; ++nc) acc[mm][nc] = (f32x4){0.f, 0.f, 0.f, 0.f};

#pragma unroll
    for (int s = 0; s < 3; ++s) {
      const int K = Ks[s];
      if (K == 0) continue;
      const int stride = K + 8;
      const int ksb = kofs[s] >> 5;
      const u16* lbase = &ldsA[soff[s] + r16 * stride + quad * 8];

#pragma unroll 2
      for (int k0 = 0; k0 < K; k0 += 32) {
        const int ks = ksb + (k0 >> 5);
        const u16* ch = Wp + (((size_t)(t * KsT + ks) * SUBS) << 9) + lane * 8;
        bf16x8 af[MM];
#pragma unroll
        for (int mm = 0; mm < MM; ++mm)
          af[mm] = *reinterpret_cast<const bf16x8*>(lbase + mm * 16 * stride + k0);
        bf16x8 whf[4], wlf[4];
#pragma unroll
        for (int nc = 0; nc < 4; ++nc) {
          whf[nc] = *reinterpret_cast<const bf16x8*>(ch + (nc << 9));
          if (SPLIT) wlf[nc] = *reinterpret_cast<const bf16x8*>(ch + ((4 + nc) << 9));
        }
#pragma unroll
        for (int mm = 0; mm < MM; ++mm)
#pragma unroll
          for (int nc = 0; nc < 4; ++nc) {
            acc[mm][nc] = __builtin_amdgcn_mfma_f32_16x16x32_bf16(whf[nc], af[mm], acc[mm][nc], 0, 0, 0);
            if (SPLIT)
              acc[mm][nc] = __builtin_amdgcn_mfma_f32_16x16x32_bf16(wlf[nc], af[mm], acc[mm][nc], 0, 0, 0);
          }
      }
    }

#pragma unroll
    for (int mm = 0; mm < MM; ++mm) {
      const int m = m0 + mm * 16 + r16;
      if (m >= M) continue;
#pragma unroll
      for (int nc = 0; nc < 4; ++nc) {
        const int n = n0w + nc * 16 + quad * 4;
        float b0 = 0.f, b1 = 0.f, b2 = 0.f, b3 = 0.f;
        if (bias) {
          float4 bv = *reinterpret_cast<const float4*>(bias + n);
          b0 = bv.x; b1 = bv.y; b2 = bv.z; b3 = bv.w;
        }
        float v0 = acc[mm][nc][0] + b0;
        float v1 = acc[mm][nc][1] + b1;
        float v2 = acc[mm][nc][2] + b2;
        float v3 = acc[mm][nc][3] + b3;
        if (BF16OUT) {
          ushort4 o = { f2bf(v0), f2bf(v1), f2bf(v2), f2bf(v3) };
          *reinterpret_cast<ushort4*>((u16*)Cv + (size_t)m * ldc + n) = o;
        } else {
          float4 o = { v0, v1, v2, v3 };
          *reinterpret_cast<float4*>((float*)Cv + (size_t)m * ldc + n) = o;
        }
      }
    }
  }
}

// ---------------------------------------------------------------------------
// Fused GATv2 aggregation (r13 math, 4-edge ILP): one wave per dst node,
// static 5000-wave schedule (4 nodes/wave). Softmax referenced to first
// edge's logit. lrelu folded: lrelu(v)*att = (0.6att)v + (0.4att)|v|.
// 4 gather/dot/shfl/exp chains in flight per iteration to cover L2/L3
// gather latency (r13 pairs -> quads).
// XLR row (u16): [xl(0..D-1) | xr(D..2D-1)].
// ---------------------------------------------------------------------------
template<int VPL>
__device__ __forceinline__ void load_row(const u16* p, float* dst) {
  if constexpr (VPL == 8) {
    uint4 t = *reinterpret_cast<const uint4*>(p);
    bf2x2(t.x, dst[0], dst[1]); bf2x2(t.y, dst[2], dst[3]);
    bf2x2(t.z, dst[4], dst[5]); bf2x2(t.w, dst[6], dst[7]);
  } else {
    uint2 t = *reinterpret_cast<const uint2*>(p);
    bf2x2(t.x, dst[0], dst[1]); bf2x2(t.y, dst[2], dst[3]);
  }
}

template<int C>
__global__ __launch_bounds__(256) void gat_node_kernel(
    const u16* __restrict__ XLR,
    const int* __restrict__ rowptr, const int* __restrict__ srcs,
    const float* __restrict__ att, const float* __restrict__ bias,
    u16* __restrict__ Hh, int Nn)
{
  constexpr int D = C * 8;
  constexpr int VPL = D / 64;
  const int lane = threadIdx.x & 63;
  const int wv  = (blockIdx.x * 256 + threadIdx.x) >> 6;
  const int nwv = (gridDim.x * 256) >> 6;

  float c1[VPL], c2[VPL], biasR[VPL];
#pragma unroll
  for (int w = 0; w < VPL; ++w) {
    float a = att[lane * VPL + w];
    c1[w] = 0.6f * a;
    c2[w] = 0.4f * a;
    biasR[w] = bias[lane * VPL + w];
  }

  for (int d = wv; d < Nn; d += nwv) {
    float xr[VPL];
    load_row<VPL>(XLR + (size_t)d * (2 * D) + D + lane * VPL, xr);

    const int jb = rowptr[d], je = rowptr[d + 1];

    // first edge = softmax reference (acc initialized to its xl row)
    float acc[VPL];
    load_row<VPL>(XLR + (size_t)srcs[jb] * (2 * D) + lane * VPL, acc);
    float p0 = 0.f;
#pragma unroll
    for (int w = 0; w < VPL; ++w) {
      float v = acc[w] + xr[w];
      p0 = fmaf(c1[w], v, fmaf(c2[w], fabsf(v), p0));
    }
    p0 += __shfl_xor(p0, 1);
    p0 += __shfl_xor(p0, 2);
    p0 += __shfl_xor(p0, 4);
    float den = 1.f;

    int j = jb + 1;
    // ---- 4-edge main loop: 4 independent gather/dot/shfl/exp chains ----
    for (; j + 3 < je; j += 4) {
      float xa[VPL], xb[VPL], xc[VPL], xd[VPL];
      load_row<VPL>(XLR + (size_t)srcs[j]     * (2 * D) + lane * VPL, xa);
      load_row<VPL>(XLR + (size_t)srcs[j + 1] * (2 * D) + lane * VPL, xb);
      load_row<VPL>(XLR + (size_t)srcs[j + 2] * (2 * D) + lane * VPL, xc);
      load_row<VPL>(XLR + (size_t)srcs[j + 3] * (2 * D) + lane * VPL, xd);
      float pa = 0.f, pb = 0.f, pc = 0.f, pd = 0.f;
#pragma unroll
      for (int w = 0; w < VPL; ++w) {
        float va = xa[w] + xr[w];
        float vb = xb[w] + xr[w];
        float vc = xc[w] + xr[w];
        float vd = xd[w] + xr[w];
        pa = fmaf(c1[w], va, fmaf(c2[w], fabsf(va), pa));
        pb = fmaf(c1[w], vb, fmaf(c2[w], fabsf(vb), pb));
        pc = fmaf(c1[w], vc, fmaf(c2[w], fabsf(vc), pc));
        pd = fmaf(c1[w], vd, fmaf(c2[w], fabsf(vd), pd));
      }
      pa += __shfl_xor(pa, 1); pb += __shfl_xor(pb, 1);
      pc += __shfl_xor(pc, 1); pd += __shfl_xor(pd, 1);
      pa += __shfl_xor(pa, 2); pb += __shfl_xor(pb, 2);
      pc += __shfl_xor(pc, 2); pd += __shfl_xor(pd, 2);
      pa += __shfl_xor(pa, 4); pb += __shfl_xor(pb, 4);
      pc += __shfl_xor(pc, 4); pd += __shfl_xor(pd, 4);
      const float ea = __expf(pa - p0);
      const float eb = __expf(pb - p0);
      const float ec = __expf(pc - p0);
      const float ed = __expf(pd - p0);
      den += (ea + eb) + (ec + ed);
#pragma unroll
      for (int w = 0; w < VPL; ++w) {
        float t0 = fmaf(ea, xa[w], fmaf(eb, xb[w], acc[w]));
        acc[w] = fmaf(ec, xc[w], fmaf(ed, xd[w], t0));
      }
    }
    // ---- 2-edge remainder ----
    if (j + 1 < je) {
      float xa[VPL], xb[VPL];
      load_row<VPL>(XLR + (size_t)srcs[j]     * (2 * D) + lane * VPL, xa);
      load_row<VPL>(XLR + (size_t)srcs[j + 1] * (2 * D) + lane * VPL, xb);
      float pa = 0.f, pb = 0.f;
#pragma unroll
      for (int w = 0; w < VPL; ++w) {
        float va = xa[w] + xr[w];
        float vb = xb[w] + xr[w];
        pa = fmaf(c1[w], va, fmaf(c2[w], fabsf(va), pa));
        pb = fmaf(c1[w], vb, fmaf(c2[w], fabsf(vb), pb));
      }
      pa += __shfl_xor(pa, 1); pb += __shfl_xor(pb, 1);
      pa += __shfl_xor(pa, 2); pb += __shfl_xor(pb, 2);
      pa += __shfl_xor(pa, 4); pb += __shfl_xor(pb, 4);
      const float ea = __expf(pa - p0);
      const float eb = __expf(pb - p0);
      den += ea + eb;
#pragma unroll
      for (int w = 0; w < VPL; ++w)
        acc[w] = fmaf(ea, xa[w], fmaf(eb, xb[w], acc[w]));
      j += 2;
    }
    // ---- 1-edge remainder ----
    if (j < je) {
      float xa[VPL];
      load_row<VPL>(XLR + (size_t)srcs[j] * (2 * D) + lane * VPL, xa);
      float pa = 0.f;
#pragma unroll
      for (int w = 0; w < VPL; ++w) {
        float va = xa[w] + xr[w];
        pa = fmaf(c1[w], va, fmaf(c2[w], fabsf(va), pa));
      }
      pa += __shfl_xor(pa, 1);
      pa += __shfl_xor(pa, 2);
      pa += __shfl_xor(pa, 4);
      const float ea = __expf(pa - p0);
      den += ea;
#pragma unroll
      for (int w = 0; w < VPL; ++w) acc[w] = fmaf(ea, xa[w], acc[w]);
    }

    const float inv = 1.f / den;
    u16* hh = Hh + (size_t)d * D + lane * VPL;
#pragma unroll
    for (int w = 0; w < VPL; ++w) {
      float v = fmaf(acc[w], inv, biasR[w]);
      v = v > 0.f ? v : (__expf(v) - 1.f);
      hh[w] = f2bf(v);
    }
  }
}

// ---------------------------------------------------------------------------

extern "C" void kernel_launch(void* const* d_in, const int* in_sizes, int n_in,
                              void* d_out, int out_size, void* d_ws, size_t ws_size,
                              hipStream_t stream) {
  const float* x     = (const float*)d_in[0];
  const int*   ei    = (const int*)d_in[1];
  const float* Wl1   = (const float*)d_in[2];
  const float* bl1   = (const float*)d_in[3];
  const float* Wr1   = (const float*)d_in[4];
  const float* br1   = (const float*)d_in[5];
  const float* att1  = (const float*)d_in[6];
  const float* bias1 = (const float*)d_in[7];
  const float* Wl2   = (const float*)d_in[8];
  const float* bl2   = (const float*)d_in[9];
  const float* Wr2   = (const float*)d_in[10];
  const float* br2   = (const float*)d_in[11];
  const float* att2  = (const float*)d_in[12];
  const float* bias2 = (const float*)d_in[13];
  const float* Wjk   = (const float*)d_in[14];
  const float* bjk   = (const float*)d_in[15];
  float* out = (float*)d_out;

  const int Nn = in_sizes[0] / 128;   // 20000
  const int E  = in_sizes[1] / 2;     // 320000
  const int ET = E + Nn;              // 340000

  const size_t nx = (size_t)Nn * 128;

  // packed weight region bases (u16 elements)
  const size_t oW1  = 0;
  const size_t oW2  = 262144;
  const size_t oWjk = 786432;
  const size_t npack = 901120;

  // workspace (~85 MB)
  char* ws = (char*)d_ws;
  size_t off = 0;
  u16* XH = (u16*)(ws + off); off += nx * 2;
  u16* Wp = (u16*)(ws + off); off += npack * 2;
  float* BC1 = (float*)(ws + off); off += 1024 * 4;
  float* BC2 = (float*)(ws + off); off += 512 * 4;
  u16* XLR1 = (u16*)(ws + off);               // [N][1024] bf16
  u16* XLR2 = XLR1;                           // [N][512]  (sequential reuse)
  off += (size_t)Nn * 1024 * 2;
  u16* H1h = (u16*)(ws + off); off += (size_t)Nn * 512 * 2;
  u16* H2h = (u16*)(ws + off); off += (size_t)Nn * 256 * 2;
  int* rowptr = (int*)(ws + off); off += (size_t)(Nn + 1) * 4;
  int* cur    = (int*)(ws + off); off += (size_t)Nn * 4;
  int* srcs   = (int*)(ws + off); off += (size_t)ET * 4;

  const int nodeblocks = 1250;   // 5000 waves x exactly 4 nodes each

  // ---------------- prep + weight pack + CSR build ----------------
  const int nprep = (int)(nx + 1536);
  prep_kernel<<<(nprep + 255) / 256, 256, 0, stream>>>(
      x, bl1, br1, bl2, br2, XH, BC1, BC2, (int)nx, nprep);
  wtrans_kernel<<<124, 256, 0, stream>>>(Wl1, Wr1, Wl2, Wr2, Wjk, Wp);
  hipMemsetAsync(cur, 0, (size_t)Nn * 4, stream);
  hist_kernel<<<(ET + 255) / 256, 256, 0, stream>>>(ei, E, ET, cur);
  scan_kernel<<<1, 1024, 0, stream>>>(cur, rowptr, Nn);
  hipMemsetAsync(cur, 0, (size_t)Nn * 4, stream);
  scatter_kernel<<<(ET + 255) / 256, 256, 0, stream>>>(ei, E, ET, rowptr, cur, srcs);

  // ---------------- Layer 1: XLR1 = XH @ [Wl1|Wr1] (2-term split) ----------
  gemmct_kernel<32, 8, 4, true, true, 32 * 136>
      <<<(Nn + 31) / 32, 512, 0, stream>>>(
      XH, 128, 128, nullptr, 0, 0, nullptr, 0, 0,
      Wp + oW1, 4, 0, 0, 0, BC1,
      XLR1, 1024, Nn, 1024);
  gat_node_kernel<64><<<nodeblocks, 256, 0, stream>>>(
      XLR1, rowptr, srcs, att1, bias1, H1h, Nn);

  // ---------------- Layer 2: XLR2 = H1h @ [Wl2|Wr2] (2-term split) ---------
  gemmct_kernel<48, 8, 4, true, true, 48 * 520>
      <<<(Nn + 47) / 48, 512, 0, stream>>>(
      H1h, 512, 512, nullptr, 0, 0, nullptr, 0, 0,
      Wp + oW2, 16, 0, 0, 0, BC2,
      XLR2, 512, Nn, 512);
  gat_node_kernel<32><<<nodeblocks, 256, 0, stream>>>(
      XLR2, rowptr, srcs, att2, bias2, H2h, Nn);

  // ---------------- JK: out = [x|h1|h2] @ Wjk + bjk (hi-only, f32 out) -----
  gemmct_kernel<16, 2, 1, false, false, 16 * 920>
      <<<(Nn + 15) / 16, 128, 0, stream>>>(
      XH, 128, 128, H1h, 512, 512, H2h, 256, 256,
      Wp + oWjk, 28, 0, 128, 640, bjk,
      out, 128, Nn, 128);
}